// Round 8
// baseline (37837.619 us; speedup 1.0000x reference)
//
#include <hip/hip_runtime.h>

#define T_STEPS 8192
#define DD 1024
#define HH 1024
#define NWG 256
#define NTHR 512
#define SCOPE_AGENT __HIP_MEMORY_SCOPE_AGENT
#define SCOPE_WG __HIP_MEMORY_SCOPE_WORKGROUP
typedef unsigned long long u64;

__device__ __forceinline__ float ftanh(float v) {
  return 2.f / (1.f + __expf(-2.f * v)) - 1.f;
}

// Fully-decoupled persistent scan. WG g owns h[4g..4g+4). No per-step
// __syncthreads; all intra-WG ordering via LDS flags + lgkmcnt, inter-WG via
// tagged 8B atoms (tag<<32 | float bits) in a 2-slot ping-pong.
//   x-waves 0-3: wave w owns x rows [w*256,+256) x 16 cols. Wave-private x
//     staging; writes xpart[p][w][16] + xflag. Throttled by xdone (lag 2).
//   h-waves 4-7: wave 4+e owns h element e: polls its 256-atom chunk, stages
//     to hb[p], sets cflag, spins 4 cflags + 4 xflags, computes the FULL
//     1024-dot for its 4 gate columns, butterfly-reduce in-wave, gates,
//     publishes its own tagged atom. No cross-wave combine, no barrier.
// LDS swizzle: value with linear idx k stored at k ^ (((k>>6)&3)<<2) so the
// 4 (or 16) seg-groups of a wave's b128 broadcast reads hit distinct bank
// quads (round-6/7 proven, 0 conflicts).
__global__ __launch_bounds__(NTHR, 1) void lstm_scan(
    const float* __restrict__ x, const float* __restrict__ c_in,
    const float* __restrict__ h_in, const float* __restrict__ W,
    const float* __restrict__ b, float* __restrict__ Hs,  // [T][H] = h_1..h_T
    u64* __restrict__ hbuf,         // [2][H] tagged ping-pong (memset 0)
    float* __restrict__ out_tail)   // c_last | h_last
{
  const int g = blockIdx.x, tid = threadIdx.x;
  const int lane = tid & 63, wave = tid >> 6;
  const bool is_x = (wave < 4);

  __shared__ float Wl[32768];       // 128 KB packed weights (16KB/wave)
  __shared__ float xc[4][256];      // wave-private x chunks
  __shared__ float hb[2][1024];     // staged h, parity slots (swizzled)
  __shared__ float xpart[2][4][16]; // x partials per chunk per column
  __shared__ int xflag[2][4];       // xpart[p][w] ready for step t
  __shared__ int cflag[2][4];       // hb[p] chunk c staged for step t
  __shared__ int xdone[2][4];       // h-wave e consumed xpart[p] at step t

  if (tid < 4) {
    xflag[0][tid] = 0; xflag[1][tid] = 0;
    cflag[0][tid] = 0; cflag[1][tid] = 0;
    xdone[0][tid] = 0; xdone[1][tid] = 0;
    // Publish h_0 (slot 0, tag 1).
    const float h0 = h_in[g * 4 + tid];
    const u64 pv = ((u64)1u << 32) | (u64)__float_as_uint(h0);
    __hip_atomic_store(&hbuf[g * 4 + tid], pv, __ATOMIC_RELAXED, SCOPE_AGENT);
  }

  // One-time weight staging into packed per-lane layout (16KB per wave).
  if (is_x) {
    const int col = lane & 15, sseg = lane >> 4;
    const int cgx = (col >> 2) * HH + g * 4 + (col & 3);
    #pragma unroll
    for (int j = 0; j < 16; ++j) {
      float4 v;
      v.x = W[(size_t)(wave * 256 + sseg * 64 + j * 4 + 0) * (4 * HH) + cgx];
      v.y = W[(size_t)(wave * 256 + sseg * 64 + j * 4 + 1) * (4 * HH) + cgx];
      v.z = W[(size_t)(wave * 256 + sseg * 64 + j * 4 + 2) * (4 * HH) + cgx];
      v.w = W[(size_t)(wave * 256 + sseg * 64 + j * 4 + 3) * (4 * HH) + cgx];
      *(float4*)&Wl[wave * 4096 + j * 256 + lane * 4] = v;
    }
  } else {
    const int e = wave - 4, gate = lane & 3, kseg = lane >> 2;
    const int cgh = gate * HH + g * 4 + e;
    #pragma unroll
    for (int j = 0; j < 16; ++j) {
      float4 v;
      v.x = W[(size_t)(DD + kseg * 64 + j * 4 + 0) * (4 * HH) + cgh];
      v.y = W[(size_t)(DD + kseg * 64 + j * 4 + 1) * (4 * HH) + cgh];
      v.z = W[(size_t)(DD + kseg * 64 + j * 4 + 2) * (4 * HH) + cgh];
      v.w = W[(size_t)(DD + kseg * 64 + j * 4 + 3) * (4 * HH) + cgh];
      *(float4*)&Wl[wave * 4096 + j * 256 + lane * 4] = v;
    }
  }

  float c_reg = 0.f, hlast = 0.f, bias_l = 0.f;
  if (!is_x) {
    bias_l = b[(lane & 3) * HH + g * 4 + (wave - 4)];
    c_reg = c_in[g * 4 + (wave - 4)];
  }

  float4 xv = make_float4(0.f, 0.f, 0.f, 0.f);
  if (is_x) xv = *(const float4*)&x[wave * 256 + lane * 4];

  __syncthreads();  // Wl + flags + h_0 publish issued

  if (is_x) {
    const int sseg = lane >> 4;
    const int sswz = (sseg & 3) << 2;
    for (int t = 1; t <= T_STEPS; ++t) {
      const int p = t & 1;
      // Stage own chunk (canonical swizzle of k=lane*4).
      *(float4*)&xc[wave][(lane * 4) ^ sswz] = xv;
      if (t < T_STEPS)
        xv = *(const float4*)&x[(size_t)t * DD + wave * 256 + lane * 4];
      asm volatile("s_waitcnt lgkmcnt(0)" ::: "memory");
      // Chunk dot for all 16 columns.
      float pa = 0.f;
      #pragma unroll
      for (int j = 0; j < 16; ++j) {
        const float4 wv = *(const float4*)&Wl[wave * 4096 + j * 256 + lane * 4];
        const float4 xq = *(const float4*)&xc[wave][(sseg * 64 + j * 4) ^ sswz];
        pa = fmaf(xq.x, wv.x, pa); pa = fmaf(xq.y, wv.y, pa);
        pa = fmaf(xq.z, wv.z, pa); pa = fmaf(xq.w, wv.w, pa);
      }
      pa += __shfl_xor(pa, 16);
      pa += __shfl_xor(pa, 32);
      // Throttle: don't overwrite xpart slot until consumed (lag 2).
      {
        const int tm2 = t - 2;
        for (;;) {
          const int d0 = __hip_atomic_load(&xdone[p][0], __ATOMIC_RELAXED, SCOPE_WG);
          const int d1 = __hip_atomic_load(&xdone[p][1], __ATOMIC_RELAXED, SCOPE_WG);
          const int d2 = __hip_atomic_load(&xdone[p][2], __ATOMIC_RELAXED, SCOPE_WG);
          const int d3 = __hip_atomic_load(&xdone[p][3], __ATOMIC_RELAXED, SCOPE_WG);
          if (d0 >= tm2 && d1 >= tm2 && d2 >= tm2 && d3 >= tm2) break;
          __builtin_amdgcn_s_sleep(1);
        }
      }
      asm volatile("" ::: "memory");
      if (lane < 16) xpart[p][wave][lane] = pa;
      asm volatile("s_waitcnt lgkmcnt(0)" ::: "memory");
      if (lane == 0)
        __hip_atomic_store(&xflag[p][wave], t, __ATOMIC_RELAXED, SCOPE_WG);
    }
  } else {
    const int e = wave - 4;
    const int gate = lane & 3, kseg = lane >> 2;
    const int kswz = (kseg & 3) << 2;
    const int cb = e * 256;
    const int colw = gate * 4 + e;  // within-WG column index
    for (int t = 1; t <= T_STEPS; ++t) {
      const int p = t & 1;
      // Poll own 256-atom chunk (4/lane), stale-only retry, no sleep.
      const u64* hp = hbuf + ((t - 1) & 1) * HH;
      const unsigned tg = (unsigned)t;
      u64 a0 = __hip_atomic_load(&hp[cb + lane],       __ATOMIC_RELAXED, SCOPE_AGENT);
      u64 a1 = __hip_atomic_load(&hp[cb + 64 + lane],  __ATOMIC_RELAXED, SCOPE_AGENT);
      u64 a2 = __hip_atomic_load(&hp[cb + 128 + lane], __ATOMIC_RELAXED, SCOPE_AGENT);
      u64 a3 = __hip_atomic_load(&hp[cb + 192 + lane], __ATOMIC_RELAXED, SCOPE_AGENT);
      bool r0 = (unsigned)(a0 >> 32) >= tg;
      bool r1 = (unsigned)(a1 >> 32) >= tg;
      bool r2 = (unsigned)(a2 >> 32) >= tg;
      bool r3 = (unsigned)(a3 >> 32) >= tg;
      while (!(r0 & r1 & r2 & r3)) {
        if (!r0) { a0 = __hip_atomic_load(&hp[cb + lane],       __ATOMIC_RELAXED, SCOPE_AGENT); r0 = (unsigned)(a0 >> 32) >= tg; }
        if (!r1) { a1 = __hip_atomic_load(&hp[cb + 64 + lane],  __ATOMIC_RELAXED, SCOPE_AGENT); r1 = (unsigned)(a1 >> 32) >= tg; }
        if (!r2) { a2 = __hip_atomic_load(&hp[cb + 128 + lane], __ATOMIC_RELAXED, SCOPE_AGENT); r2 = (unsigned)(a2 >> 32) >= tg; }
        if (!r3) { a3 = __hip_atomic_load(&hp[cb + 192 + lane], __ATOMIC_RELAXED, SCOPE_AGENT); r3 = (unsigned)(a3 >> 32) >= tg; }
      }
      // Stage own chunk at canonical swizzle (k>>6 &3 == j2 here).
      hb[p][(cb + lane)]            = __uint_as_float((unsigned)a0);
      hb[p][(cb + 64 + lane) ^ 4]   = __uint_as_float((unsigned)a1);
      hb[p][(cb + 128 + lane) ^ 8]  = __uint_as_float((unsigned)a2);
      hb[p][(cb + 192 + lane) ^ 12] = __uint_as_float((unsigned)a3);
      asm volatile("s_waitcnt lgkmcnt(0)" ::: "memory");
      if (lane == 0)
        __hip_atomic_store(&cflag[p][e], t, __ATOMIC_RELAXED, SCOPE_WG);
      // Spin: all 4 chunks staged + all 4 x-partials published (LDS, fast).
      for (;;) {
        const int c0 = __hip_atomic_load(&cflag[p][0], __ATOMIC_RELAXED, SCOPE_WG);
        const int c1 = __hip_atomic_load(&cflag[p][1], __ATOMIC_RELAXED, SCOPE_WG);
        const int c2 = __hip_atomic_load(&cflag[p][2], __ATOMIC_RELAXED, SCOPE_WG);
        const int c3 = __hip_atomic_load(&cflag[p][3], __ATOMIC_RELAXED, SCOPE_WG);
        const int f0 = __hip_atomic_load(&xflag[p][0], __ATOMIC_RELAXED, SCOPE_WG);
        const int f1 = __hip_atomic_load(&xflag[p][1], __ATOMIC_RELAXED, SCOPE_WG);
        const int f2 = __hip_atomic_load(&xflag[p][2], __ATOMIC_RELAXED, SCOPE_WG);
        const int f3 = __hip_atomic_load(&xflag[p][3], __ATOMIC_RELAXED, SCOPE_WG);
        if (c0 >= t && c1 >= t && c2 >= t && c3 >= t &&
            f0 >= t && f1 >= t && f2 >= t && f3 >= t) break;
      }
      asm volatile("" ::: "memory");
      // Full-1024 h-dot for this wave's 4 gate columns.
      float q = 0.f;
      #pragma unroll
      for (int j = 0; j < 16; ++j) {
        const float4 wv = *(const float4*)&Wl[wave * 4096 + j * 256 + lane * 4];
        const float4 hv = *(const float4*)&hb[p][(kseg * 64 + j * 4) ^ kswz];
        q = fmaf(hv.x, wv.x, q); q = fmaf(hv.y, wv.y, q);
        q = fmaf(hv.z, wv.z, q); q = fmaf(hv.w, wv.w, q);
      }
      // Butterfly over the 16 ksegs (lanes differing in bits 2..5).
      q += __shfl_xor(q, 4);
      q += __shfl_xor(q, 8);
      q += __shfl_xor(q, 16);
      q += __shfl_xor(q, 32);
      const float z = bias_l + q +
                      xpart[p][0][colw] + xpart[p][1][colw] +
                      xpart[p][2][colw] + xpart[p][3][colw];
      // Uniform activation per gate lane: i,f,o -> sigmoid (f with +1),
      // j -> tanh via 2*sig(2z)-1. One exp each, no divergence.
      const float zin = (gate == 1) ? (2.f * z) : (gate == 2 ? z + 1.f : z);
      const float s = 1.f / (1.f + __expf(-zin));
      const float act = (gate == 1) ? (2.f * s - 1.f) : s;
      const float ig = __shfl(act, 0);
      const float tj = __shfl(act, 1);
      const float fg = __shfl(act, 2);
      const float og = __shfl(act, 3);
      const float nc = c_reg * fg + ig * tj;
      const float nh = ftanh(nc) * og;
      c_reg = nc; hlast = nh;
      if (lane == 0) {
        const u64 pv = ((u64)(unsigned)(t + 1) << 32) | (u64)__float_as_uint(nh);
        __hip_atomic_store(&hbuf[(t & 1) * HH + g * 4 + e], pv,
                           __ATOMIC_RELAXED, SCOPE_AGENT);
        Hs[(size_t)(t - 1) * HH + g * 4 + e] = nh;  // fire-and-forget
      }
      // Ack xpart consumption (xpart reads drained by the lgkm-free data dep;
      // enforce with an explicit wait before the flag).
      asm volatile("s_waitcnt lgkmcnt(0)" ::: "memory");
      if (lane == 0)
        __hip_atomic_store(&xdone[p][e], t, __ATOMIC_RELAXED, SCOPE_WG);
    }
    if (lane == 0) {
      out_tail[g * 4 + e]      = c_reg;   // c_last
      out_tail[HH + g * 4 + e] = hlast;   // h_last
    }
  }
}

// output = hs @ W_out + b_out. fp32 tiled GEMM, 64x64 tile, 4x4/thread.
#define BM 64
#define BN 64
#define BK 16
__global__ __launch_bounds__(256, 2) void out_gemm(
    const float* __restrict__ A,    // hs [8192][1024]
    const float* __restrict__ Bw,   // W_out [1024][1024]
    const float* __restrict__ bias,
    float* __restrict__ C)          // [8192][1024]
{
  __shared__ float As[BM][BK];
  __shared__ float Bs[BK][BN];
  const int tid = threadIdx.x;
  const int row0 = blockIdx.y * BM, col0 = blockIdx.x * BN;
  const int tx = tid & 15, ty = tid >> 4;

  float acc[4][4];
  #pragma unroll
  for (int j = 0; j < 4; ++j) {
    const float bv = bias[col0 + tx * 4 + j];
    #pragma unroll
    for (int i = 0; i < 4; ++i) acc[i][j] = bv;
  }

  for (int k0 = 0; k0 < HH; k0 += BK) {
    {
      const int r = tid >> 2, c = (tid & 3) * 4;
      const float4 va = *(const float4*)&A[(size_t)(row0 + r) * HH + k0 + c];
      As[r][c] = va.x; As[r][c + 1] = va.y; As[r][c + 2] = va.z; As[r][c + 3] = va.w;
      const int rb = tid >> 4, cb = (tid & 15) * 4;
      *(float4*)&Bs[rb][cb] = *(const float4*)&Bw[(size_t)(k0 + rb) * HH + col0 + cb];
    }
    __syncthreads();
    #pragma unroll
    for (int kk = 0; kk < BK; ++kk) {
      float a[4], bv[4];
      #pragma unroll
      for (int i = 0; i < 4; ++i) a[i] = As[ty * 4 + i][kk];
      #pragma unroll
      for (int j = 0; j < 4; ++j) bv[j] = Bs[kk][tx * 4 + j];
      #pragma unroll
      for (int i = 0; i < 4; ++i)
        #pragma unroll
        for (int j = 0; j < 4; ++j)
          acc[i][j] = fmaf(a[i], bv[j], acc[i][j]);
    }
    __syncthreads();
  }

  #pragma unroll
  for (int i = 0; i < 4; ++i) {
    float4 v = make_float4(acc[i][0], acc[i][1], acc[i][2], acc[i][3]);
    *(float4*)&C[(size_t)(row0 + ty * 4 + i) * HH + col0 + tx * 4] = v;
  }
}

extern "C" void kernel_launch(void* const* d_in, const int* in_sizes, int n_in,
                              void* d_out, int out_size, void* d_ws, size_t ws_size,
                              hipStream_t stream) {
  const float* x    = (const float*)d_in[0];
  const float* c_in = (const float*)d_in[1];
  const float* h_in = (const float*)d_in[2];
  const float* W    = (const float*)d_in[3];
  const float* b    = (const float*)d_in[4];
  const float* Wout = (const float*)d_in[5];
  const float* bout = (const float*)d_in[6];
  float* out = (float*)d_out;

  // ws layout: hbuf [2*H u64, 16KB] | Hs [T*H floats, 32MB]
  u64* hbuf = (u64*)d_ws;
  float* Hs = (float*)(hbuf + 2 * HH);
  float* out_tail = out + (size_t)T_STEPS * HH;

  // Tags must start at 0 every launch (graph replays reuse ws).
  hipMemsetAsync(hbuf, 0, 2 * HH * sizeof(u64), stream);

  void* args[] = {(void*)&x, (void*)&c_in, (void*)&h_in, (void*)&W, (void*)&b,
                  (void*)&Hs, (void*)&hbuf, (void*)&out_tail};
  hipLaunchCooperativeKernel((void*)lstm_scan, dim3(NWG), dim3(NTHR),
                             args, 0, stream);

  out_gemm<<<dim3(HH / BN, T_STEPS / BM), 256, 0, stream>>>(Hs, Wout, bout, out);
}

// Round 10
// 12980.263 us; speedup vs baseline: 2.9150x; 2.9150x over previous
//
#include <hip/hip_runtime.h>

#define T_STEPS 8192
#define DD 1024
#define HH 1024
#define NWG 256
#define NTHR 512
#define SCOPE_AGENT __HIP_MEMORY_SCOPE_AGENT
typedef unsigned long long u64;

// XOR swizzle (float index) so the 4 segs of a wave hit distinct bank quads
// when broadcasting 16B chunks to 16 lanes each.
__device__ __forceinline__ int swz(int k) { return k ^ ((((k) >> 6) & 3) << 2); }

__device__ __forceinline__ float fsig(float v) {
  return 1.f / (1.f + __expf(-v));
}
__device__ __forceinline__ float ftanh(float v) {
  return 2.f / (1.f + __expf(-2.f * v)) - 1.f;
}

// ROUND-7 PROVEN SCAN (12.97 ms) — kept byte-identical. Round-8's fully
// decoupled variant regressed 3x: h-waves with no pre-poll work arrive early
// and spin at agent scope, congesting L3/fabric and slowing the publishes
// themselves. Lesson: poll arrival time must match producer visibility.
__global__ __launch_bounds__(NTHR, 1) void lstm_scan(
    const float* __restrict__ x, const float* __restrict__ c_in,
    const float* __restrict__ h_in, const float* __restrict__ W,
    const float* __restrict__ b, float* __restrict__ Hs,  // [T][H] = h_1..h_T
    u64* __restrict__ hbuf,         // [2][H] tagged ping-pong (memset 0)
    float* __restrict__ out_tail)   // c_last | h_last
{
  const int g = blockIdx.x, tid = threadIdx.x;
  const int lane = tid & 63, wave = tid >> 6;
  const int col = tid & 15, seg = tid >> 4;
  const int gate = col >> 2, hi = col & 3;
  const int cg = gate * HH + g * 4 + hi;

  __shared__ float Wl[32768];       // 128 KB packed weight slice
  __shared__ float xb[DD];          // swizzled x_t
  __shared__ float hb[HH];          // swizzled h_{t-1} (per-wave chunks)
  __shared__ float partial[8][16];  // per-wave column partials

  float c_reg = 0.f, hlast = 0.f;

  // Publish h_0 immediately (slot 0, tag 1).
  if (tid < 4) {
    const float h0 = h_in[g * 4 + tid];
    c_reg = c_in[g * 4 + tid];
    const u64 pv = ((u64)1u << 32) | (u64)__float_as_uint(h0);
    __hip_atomic_store(&hbuf[g * 4 + tid], pv, __ATOMIC_RELAXED, SCOPE_AGENT);
  }

  // One-time weight staging: 64 strided global loads -> packed LDS.
  #pragma unroll
  for (int j = 0; j < 16; ++j) {
    float4 v;
    v.x = W[(size_t)(seg * 64 + j * 4 + 0) * (4 * HH) + cg];
    v.y = W[(size_t)(seg * 64 + j * 4 + 1) * (4 * HH) + cg];
    v.z = W[(size_t)(seg * 64 + j * 4 + 2) * (4 * HH) + cg];
    v.w = W[(size_t)(seg * 64 + j * 4 + 3) * (4 * HH) + cg];
    *(float4*)&Wl[(wave * 16 + j) * 256 + lane * 4] = v;
  }

  // Loop-invariant bias for this thread's column (used by wave 0 only).
  const float bias_reg = b[((lane & 15) >> 2) * HH + g * 4 + (lane & 3)];

  // Prefetch x_1 into registers.
  float xv0 = x[tid], xv1 = x[tid + 512];

  __syncthreads();  // Wl ready

  const bool is_x = (wave < 4);

  for (int t = 1; t <= T_STEPS; ++t) {
    // A: stage x_t from prefetch regs.
    xb[swz(tid)]       = xv0;
    xb[swz(tid + 512)] = xv1;
    __syncthreads();  // xb ready; partial[] + xb reuse guarded

    // Prefetch x_{t+1} (non-blocking; consumed at next A).
    if (t < T_STEPS) {
      const float* xn = x + (size_t)t * DD;
      xv0 = xn[tid];
      xv1 = xn[tid + 512];
    }

    if (is_x) {
      // x-half dot over segs 0..15.
      float p = 0.f;
      #pragma unroll
      for (int j = 0; j < 16; ++j) {
        const float4 wv = *(const float4*)&Wl[(wave * 16 + j) * 256 + lane * 4];
        const float4 xv = *(const float4*)&xb[(seg * 64 + j * 4) ^ ((seg & 3) << 2)];
        p = fmaf(xv.x, wv.x, p); p = fmaf(xv.y, wv.y, p);
        p = fmaf(xv.z, wv.z, p); p = fmaf(xv.w, wv.w, p);
      }
      p += __shfl_xor(p, 16);
      p += __shfl_xor(p, 32);
      if (lane < 16) partial[wave][lane] = p;
    } else {
      // h-wave: poll own 256-atom chunk (4/lane), no sleep, stale-only retry.
      const u64* hp = hbuf + ((t - 1) & 1) * HH;
      const int cb = (wave - 4) * 256;
      const unsigned tg = (unsigned)t;
      u64 a0 = __hip_atomic_load(&hp[cb + lane],       __ATOMIC_RELAXED, SCOPE_AGENT);
      u64 a1 = __hip_atomic_load(&hp[cb + 64 + lane],  __ATOMIC_RELAXED, SCOPE_AGENT);
      u64 a2 = __hip_atomic_load(&hp[cb + 128 + lane], __ATOMIC_RELAXED, SCOPE_AGENT);
      u64 a3 = __hip_atomic_load(&hp[cb + 192 + lane], __ATOMIC_RELAXED, SCOPE_AGENT);
      bool r0 = (unsigned)(a0 >> 32) >= tg;
      bool r1 = (unsigned)(a1 >> 32) >= tg;
      bool r2 = (unsigned)(a2 >> 32) >= tg;
      bool r3 = (unsigned)(a3 >> 32) >= tg;
      while (!(r0 & r1 & r2 & r3)) {
        if (!r0) { a0 = __hip_atomic_load(&hp[cb + lane],       __ATOMIC_RELAXED, SCOPE_AGENT); r0 = (unsigned)(a0 >> 32) >= tg; }
        if (!r1) { a1 = __hip_atomic_load(&hp[cb + 64 + lane],  __ATOMIC_RELAXED, SCOPE_AGENT); r1 = (unsigned)(a1 >> 32) >= tg; }
        if (!r2) { a2 = __hip_atomic_load(&hp[cb + 128 + lane], __ATOMIC_RELAXED, SCOPE_AGENT); r2 = (unsigned)(a2 >> 32) >= tg; }
        if (!r3) { a3 = __hip_atomic_load(&hp[cb + 192 + lane], __ATOMIC_RELAXED, SCOPE_AGENT); r3 = (unsigned)(a3 >> 32) >= tg; }
      }
      // Stage own chunk (2 lanes/bank after swizzle -> free).
      hb[swz(cb + lane)]       = __uint_as_float((unsigned)a0);
      hb[swz(cb + 64 + lane)]  = __uint_as_float((unsigned)a1);
      hb[swz(cb + 128 + lane)] = __uint_as_float((unsigned)a2);
      hb[swz(cb + 192 + lane)] = __uint_as_float((unsigned)a3);
      // Same-wave LDS write->read: lgkmcnt(0) is sufficient, no barrier.
      asm volatile("s_waitcnt lgkmcnt(0)" ::: "memory");
      // h-half dot over own chunk (segs s2 = (wave-4)*4 + (lane>>4)).
      const int s2 = seg - 16;
      float q = 0.f;
      #pragma unroll
      for (int j = 0; j < 16; ++j) {
        const float4 wv = *(const float4*)&Wl[(wave * 16 + j) * 256 + lane * 4];
        const float4 hv = *(const float4*)&hb[(s2 * 64 + j * 4) ^ ((s2 & 3) << 2)];
        q = fmaf(hv.x, wv.x, q); q = fmaf(hv.y, wv.y, q);
        q = fmaf(hv.z, wv.z, q); q = fmaf(hv.w, wv.w, q);
      }
      q += __shfl_xor(q, 16);
      q += __shfl_xor(q, 32);
      if (lane < 16) partial[wave][lane] = q;
    }
    __syncthreads();  // all 8 partial rows ready

    // E: wave 0 combines, parallel activations on 16 lanes, publishes.
    if (wave == 0) {
      float zsum = bias_reg;
      #pragma unroll
      for (int wv = 0; wv < 8; ++wv) zsum += partial[wv][lane & 15];
      // Uniform activation: gates i,f,o -> sigmoid (f with +1); j -> tanh
      // via tanh(z) = 2*sig(2z) - 1. One __expf, no divergence.
      const int gt = (lane & 15) >> 2;
      const float zin = (gt == 1) ? (2.f * zsum) : (gt == 2 ? zsum + 1.f : zsum);
      const float s = 1.f / (1.f + __expf(-zin));
      const float act = (gt == 1) ? (2.f * s - 1.f) : s;
      const float ig = __shfl(act, tid);        // lanes 0..3 gather their gates
      const float tj = __shfl(act, tid + 4);
      const float fg = __shfl(act, tid + 8);
      const float og = __shfl(act, tid + 12);
      if (tid < 4) {
        const float nc = c_reg * fg + ig * tj;
        const float nh = ftanh(nc) * og;        // single serial transcendental
        c_reg = nc; hlast = nh;
        const u64 pv = ((u64)(unsigned)(t + 1) << 32) | (u64)__float_as_uint(nh);
        __hip_atomic_store(&hbuf[(t & 1) * HH + g * 4 + tid], pv,
                           __ATOMIC_RELAXED, SCOPE_AGENT);
        Hs[(size_t)(t - 1) * HH + g * 4 + tid] = nh;  // fire-and-forget
      }
    }
  }

  if (tid < 4) {
    out_tail[g * 4 + tid]      = c_reg;   // c_last
    out_tail[HH + g * 4 + tid] = hlast;   // h_last
  }
}

// output = hs @ W_out + b_out. fp32 GEMM, 128x128 tile, 8x8/thread, BK=16.
// As stored transposed [BK][BM+4]. Bs columns get a PER-FLOAT4 bank-quad
// XOR swizzle: each 4-col group at float-index c moves to c ^ (((c>>5)&1)<<2)
// — an involution WITHIN each 8-block (r9 bug: applying the group swizzle
// only to the 8-block base overflowed into the neighbor block; swizzles must
// be the same bijective involution on write and read, element-group-wise).
#define BM 128
#define BN 128
#define BK 16
__device__ __forceinline__ int bswz(int c) { return c ^ (((c >> 5) & 1) << 2); }

__global__ __launch_bounds__(256, 2) void out_gemm(
    const float* __restrict__ A,    // hs [8192][1024]
    const float* __restrict__ Bw,   // W_out [1024][1024]
    const float* __restrict__ bias,
    float* __restrict__ C)          // [8192][1024]
{
  __shared__ float As[BK][BM + 4];
  __shared__ float Bs[BK][BN + 4];
  const int tid = threadIdx.x;
  const int row0 = blockIdx.y * BM, col0 = blockIdx.x * BN;
  const int tx = tid & 15, ty = tid >> 4;   // 16x16 thread grid

  const int ar = tid >> 1;           // 0..127  (A tile row)
  const int ac = (tid & 1) * 8;      // 0 or 8  (A tile col base)
  const int br = tid >> 4;           // 0..15   (B tile row)
  const int bc = (tid & 15) * 8;     // 0..120  (B tile col base)

  float acc[8][8];
  #pragma unroll
  for (int i = 0; i < 8; ++i)
    #pragma unroll
    for (int j = 0; j < 8; ++j) acc[i][j] = 0.f;

  for (int k0 = 0; k0 < HH; k0 += BK) {
    const float4 a0 = *(const float4*)&A[(size_t)(row0 + ar) * HH + k0 + ac];
    const float4 a1 = *(const float4*)&A[(size_t)(row0 + ar) * HH + k0 + ac + 4];
    const float4 b0 = *(const float4*)&Bw[(size_t)(k0 + br) * HH + col0 + bc];
    const float4 b1 = *(const float4*)&Bw[(size_t)(k0 + br) * HH + col0 + bc + 4];
    As[ac + 0][ar] = a0.x; As[ac + 1][ar] = a0.y;
    As[ac + 2][ar] = a0.z; As[ac + 3][ar] = a0.w;
    As[ac + 4][ar] = a1.x; As[ac + 5][ar] = a1.y;
    As[ac + 6][ar] = a1.z; As[ac + 7][ar] = a1.w;
    *(float4*)&Bs[br][bswz(bc)]     = b0;   // per-group involution:
    *(float4*)&Bs[br][bswz(bc + 4)] = b1;   // both stay inside the 8-block
    __syncthreads();
    #pragma unroll
    for (int kk = 0; kk < BK; ++kk) {
      float a[8], bb[8];
      *(float4*)&a[0]  = *(const float4*)&As[kk][ty * 8];
      *(float4*)&a[4]  = *(const float4*)&As[kk][ty * 8 + 4];
      *(float4*)&bb[0] = *(const float4*)&Bs[kk][bswz(tx * 8)];
      *(float4*)&bb[4] = *(const float4*)&Bs[kk][bswz(tx * 8 + 4)];
      #pragma unroll
      for (int i = 0; i < 8; ++i)
        #pragma unroll
        for (int j = 0; j < 8; ++j)
          acc[i][j] = fmaf(a[i], bb[j], acc[i][j]);
    }
    __syncthreads();
  }

  #pragma unroll
  for (int i = 0; i < 8; ++i) {
    const size_t r = (size_t)(row0 + ty * 8 + i) * HH;
    #pragma unroll
    for (int j = 0; j < 8; j += 4) {
      float4 v;
      v.x = acc[i][j + 0] + bias[col0 + tx * 8 + j + 0];
      v.y = acc[i][j + 1] + bias[col0 + tx * 8 + j + 1];
      v.z = acc[i][j + 2] + bias[col0 + tx * 8 + j + 2];
      v.w = acc[i][j + 3] + bias[col0 + tx * 8 + j + 3];
      *(float4*)&C[r + col0 + tx * 8 + j] = v;
    }
  }
}

extern "C" void kernel_launch(void* const* d_in, const int* in_sizes, int n_in,
                              void* d_out, int out_size, void* d_ws, size_t ws_size,
                              hipStream_t stream) {
  const float* x    = (const float*)d_in[0];
  const float* c_in = (const float*)d_in[1];
  const float* h_in = (const float*)d_in[2];
  const float* W    = (const float*)d_in[3];
  const float* b    = (const float*)d_in[4];
  const float* Wout = (const float*)d_in[5];
  const float* bout = (const float*)d_in[6];
  float* out = (float*)d_out;

  // ws layout: hbuf [2*H u64, 16KB] | Hs [T*H floats, 32MB]
  u64* hbuf = (u64*)d_ws;
  float* Hs = (float*)(hbuf + 2 * HH);
  float* out_tail = out + (size_t)T_STEPS * HH;

  // Tags must start at 0 every launch (graph replays reuse ws).
  hipMemsetAsync(hbuf, 0, 2 * HH * sizeof(u64), stream);

  void* args[] = {(void*)&x, (void*)&c_in, (void*)&h_in, (void*)&W, (void*)&b,
                  (void*)&Hs, (void*)&hbuf, (void*)&out_tail};
  hipLaunchCooperativeKernel((void*)lstm_scan, dim3(NWG), dim3(NTHR),
                             args, 0, stream);

  out_gemm<<<dim3(HH / BN, T_STEPS / BM), 256, 0, stream>>>(Hs, Wout, bout, out);
}